// Round 4
// baseline (657.809 us; speedup 1.0000x reference)
//
#include <hip/hip_runtime.h>
#include <hip/hip_bf16.h>

// Fused kernel for MDI_2422361555492 on gfx950.
// Per row: pa,pb from 2x2 adjacency closed form; GCN via linearity
// (gm=em@W, gd=ed@W, combine in epilogue); attention via bilinear M=Wq@Wk^T;
// V-mix before projection; MLP head.
// R4: switched 32x32x16 -> 16x16x32 MFMA (16 rows/wave). Per-lane arrays
// halve to 16 regs each (64 total), acc = float4, zero LDS, no barriers.
// launch_bounds(256,3): 170-reg cap, 12 waves/CU. Kills the ~50-reg spill
// that R1-R3 carried (WRITE_SIZE 112 MB -> ~1 MB expected).
// Slot convention (lane = g*16+n, n = X-row): slot s in [0,32) holds column
// Q(s,g) = 16*(s>>2) + 4g + (s&3). Weight A-frags packed so GEMM output slot
// t = 4cb+q delivers column 16cb+4g+q = Q(t,g): outputs feed next GEMM
// directly from registers. Position-based pairing of A/B slots makes this
// robust to intra-slot k-order (method validated in R1 for 32x32).

typedef __attribute__((ext_vector_type(8))) short short8;
typedef __attribute__((ext_vector_type(4))) float f32x4;

__device__ __forceinline__ short bf16rne(float f) {
    unsigned int u = __builtin_bit_cast(unsigned int, f);
    u = (u + 0x7fffu + ((u >> 16) & 1u)) >> 16;
    return (short)u;
}
__device__ __forceinline__ float bf2f(short s) {
    unsigned int u = ((unsigned int)(unsigned short)s) << 16;
    return __builtin_bit_cast(float, u);
}

// ---- prologue 1: M = Wq @ Wk^T  (128x128, fp32), Wk staged in padded LDS ----
__global__ void k_matmul_qkT(const float* __restrict__ Wq, const float* __restrict__ Wk,
                             float* __restrict__ M) {
    __shared__ float lds[128 * 129];
    for (int i = threadIdx.x; i < 16384; i += 256) {
        lds[(i >> 7) * 129 + (i & 127)] = Wk[i];
    }
    __syncthreads();
    int idx = blockIdx.x * 256 + threadIdx.x;          // 64 blocks x 256
    int a = idx >> 7, b = idx & 127;
    float s = 0.f;
#pragma unroll 8
    for (int c = 0; c < 128; ++c) s += Wq[a * 128 + c] * lds[b * 129 + c];
    M[idx] = s;
}

// ---- prologue 2: pack 6 matrices into bf16 A-fragments (16x16x32 layout) ----
// dst[(((mat*8+cb)*4+kb)*64 + lane)*8 + j] =
//   bf16( W[32*kb + 16*(j>>2) + 4*(lane>>4) + (j&3)][16*cb + (lane&15)] )
__global__ void k_pack(const float* __restrict__ W0, const float* __restrict__ W1,
                       const float* __restrict__ W2, const float* __restrict__ W3,
                       const float* __restrict__ W4, const float* __restrict__ W5,
                       unsigned short* __restrict__ dst) {
    int idx = blockIdx.x * blockDim.x + threadIdx.x;   // 6*16384 threads
    int mat = idx >> 14;
    int r = idx & 16383;
    int j = r & 7;
    int lane = (r >> 3) & 63;
    int kb = (r >> 9) & 3;
    int cb = (r >> 11) & 7;
    const float* W = mat == 0 ? W0 : mat == 1 ? W1 : mat == 2 ? W2
                   : mat == 3 ? W3 : mat == 4 ? W4 : W5;
    int f = 32 * kb + 16 * (j >> 2) + 4 * (lane >> 4) + (j & 3);
    int col = 16 * cb + (lane & 15);
    float v = W[f * 128 + col];
    unsigned int u = __builtin_bit_cast(unsigned int, v);
    u = (u + 0x7fffu + ((u >> 16) & 1u)) >> 16;
    dst[idx] = (unsigned short)u;
}

// one 16-column block (cb) of X @ W_mat for 16 rows; consumed immediately
__device__ __forceinline__ f32x4 gemm_cb(const short8* __restrict__ fragp, int lane,
                                         int mat, int cb, const short8 (&x)[4]) {
    f32x4 a = {0.f, 0.f, 0.f, 0.f};
#pragma unroll
    for (int kb = 0; kb < 4; ++kb) {
        short8 wf = fragp[((mat * 8 + cb) * 4 + kb) * 64 + lane];
        a = __builtin_amdgcn_mfma_f32_16x16x32_bf16(wf, x[kb], a, 0, 0, 0);
    }
    return a;
}

__launch_bounds__(256, 3)
__global__ void k_main(const float* __restrict__ em, const float* __restrict__ ed,
                       const unsigned short* __restrict__ frags,
                       const float* __restrict__ w2, float* __restrict__ out) {
    const int tid = threadIdx.x;
    const int lane = tid & 63;
    const int n = lane & 15;
    const int g = lane >> 4;
    const int wave = (int)((blockIdx.x * blockDim.x + tid) >> 6);
    const long row = (long)wave * 16 + n;
    const float* emr = em + row * 128;
    const float* edr = ed + row * 128;
    const short8* fragp = (const short8*)frags;

    short8 em_f[4], ed_f[4], t1[4], t2[4];
    float s_mm = 0.f, s_dd = 0.f, s_md = 0.f, s_ab = 0.f;

    // load em/ed in slot order (lane (g,n), cb -> cols 16cb+4g..+3); reductions on the fly
#pragma unroll
    for (int cb = 0; cb < 8; ++cb) {
        const int col = 16 * cb + 4 * g;
        float4 vm = *(const float4*)(emr + col);
        float4 vd = *(const float4*)(edr + col);
        s_mm += vm.x * vm.x + vm.y * vm.y + vm.z * vm.z + vm.w * vm.w;
        s_dd += vd.x * vd.x + vd.y * vd.y + vd.z * vd.z + vd.w * vd.w;
        s_md += vm.x * vd.x + vm.y * vd.y + vm.z * vd.z + vm.w * vd.w;
        s_ab += fabsf(vm.x - vd.x) + fabsf(vm.y - vd.y) + fabsf(vm.z - vd.z) + fabsf(vm.w - vd.w);
        const int c = cb >> 1, jb = (cb & 1) * 4;
        em_f[c][jb + 0] = bf16rne(vm.x);
        em_f[c][jb + 1] = bf16rne(vm.y);
        em_f[c][jb + 2] = bf16rne(vm.z);
        em_f[c][jb + 3] = bf16rne(vm.w);
        ed_f[c][jb + 0] = bf16rne(vd.x);
        ed_f[c][jb + 1] = bf16rne(vd.y);
        ed_f[c][jb + 2] = bf16rne(vd.z);
        ed_f[c][jb + 3] = bf16rne(vd.w);
    }
    s_mm += __shfl_xor(s_mm, 16); s_mm += __shfl_xor(s_mm, 32);
    s_dd += __shfl_xor(s_dd, 16); s_dd += __shfl_xor(s_dd, 32);
    s_md += __shfl_xor(s_md, 16); s_md += __shfl_xor(s_md, 32);
    s_ab += __shfl_xor(s_ab, 16); s_ab += __shfl_xor(s_ab, 32);

    // adjacency closed form: pL = min(pL_cos, pL_manh), both [[a,b],[b,a]]
    const float m_ = s_ab;                             // manh off-diag >= 0, lrelu = id
    const float a3 = 1.f / (1.f + m_);
    const float b3 = m_ * a3;
    float cosv = s_md * rsqrtf((s_mm + 1e-8f) * (s_dd + 1e-8f));
    float cl = cosv < 0.f ? 0.01f * cosv : cosv;       // leaky_relu 0.01
    const float a1n = 1.f / (1.f + cl);
    const float b1 = cl * a1n;
    const float pa = fminf(a1n, a3);
    const float pb = fminf(b1, b3);

    // ---- GCN: gm = em@W, gd = ed@W, one frag load per MFMA pair ----
#pragma unroll
    for (int cb = 0; cb < 8; ++cb) {
        f32x4 gm = {0.f, 0.f, 0.f, 0.f};
        f32x4 gd = {0.f, 0.f, 0.f, 0.f};
#pragma unroll
        for (int kb = 0; kb < 4; ++kb) {
            short8 wf = fragp[(cb * 4 + kb) * 64 + lane];
            gm = __builtin_amdgcn_mfma_f32_16x16x32_bf16(wf, em_f[kb], gm, 0, 0, 0);
            gd = __builtin_amdgcn_mfma_f32_16x16x32_bf16(wf, ed_f[kb], gd, 0, 0, 0);
        }
        const int c = cb >> 1, jb = (cb & 1) * 4;
#pragma unroll
        for (int q = 0; q < 4; ++q) {
            float vm = pa * gm[q] + pb * gd[q];
            float vd = pb * gm[q] + pa * gd[q];
            vm = vm > 0.f ? vm : 0.f;
            vd = vd > 0.f ? vd : 0.f;
            t1[c][jb + q] = bf16rne(vm + bf2f(em_f[c][jb + q]));
            t2[c][jb + q] = bf16rne(vd + bf2f(ed_f[c][jb + q]));
        }
    }
    __builtin_amdgcn_sched_barrier(0);

    const float isq = 0.08838834764831845f;            // 1/sqrt(128)

    // ---- m attention: t_m = x1_m@M_m ; logits ; mix ; mLA = mix@Wv_m ----
    float l0 = 0.f, l1 = 0.f;
#pragma unroll
    for (int cb = 0; cb < 8; ++cb) {
        f32x4 tv = gemm_cb(fragp, lane, 1, cb, t1);
        const int c = cb >> 1, jb = (cb & 1) * 4;
#pragma unroll
        for (int q = 0; q < 4; ++q) {
            l0 += tv[q] * bf2f(em_f[c][jb + q]);
            l1 += tv[q] * bf2f(t1[c][jb + q]);
        }
    }
    l0 += __shfl_xor(l0, 16); l0 += __shfl_xor(l0, 32);
    l1 += __shfl_xor(l1, 16); l1 += __shfl_xor(l1, 32);
    l0 *= isq; l1 *= isq;
    {
        float mx = fmaxf(l0, l1);
        float e0 = __expf(l0 - mx), e1 = __expf(l1 - mx);
        float inv = 1.f / (e0 + e1);
        float aw0 = e0 * inv, aw1 = e1 * inv;
#pragma unroll
        for (int c = 0; c < 4; ++c)
#pragma unroll
            for (int j = 0; j < 8; ++j)
                t1[c][j] = bf16rne(aw0 * bf2f(em_f[c][j]) + aw1 * bf2f(t1[c][j]));
    }
    __builtin_amdgcn_sched_barrier(0);
    // mLA -> em_f (em dead after this point)
#pragma unroll
    for (int cb = 0; cb < 8; ++cb) {
        f32x4 v = gemm_cb(fragp, lane, 3, cb, t1);
        const int c = cb >> 1, jb = (cb & 1) * 4;
#pragma unroll
        for (int q = 0; q < 4; ++q) em_f[c][jb + q] = bf16rne(v[q]);
    }
    __builtin_amdgcn_sched_barrier(0);

    // ---- d attention ----
    float l0d = 0.f, l1d = 0.f;
#pragma unroll
    for (int cb = 0; cb < 8; ++cb) {
        f32x4 tv = gemm_cb(fragp, lane, 2, cb, t2);
        const int c = cb >> 1, jb = (cb & 1) * 4;
#pragma unroll
        for (int q = 0; q < 4; ++q) {
            l0d += tv[q] * bf2f(ed_f[c][jb + q]);
            l1d += tv[q] * bf2f(t2[c][jb + q]);
        }
    }
    l0d += __shfl_xor(l0d, 16); l0d += __shfl_xor(l0d, 32);
    l1d += __shfl_xor(l1d, 16); l1d += __shfl_xor(l1d, 32);
    l0d *= isq; l1d *= isq;
    {
        float mx = fmaxf(l0d, l1d);
        float e0 = __expf(l0d - mx), e1 = __expf(l1d - mx);
        float inv = 1.f / (e0 + e1);
        float aw0 = e0 * inv, aw1 = e1 * inv;
#pragma unroll
        for (int c = 0; c < 4; ++c)
#pragma unroll
            for (int j = 0; j < 8; ++j)
                t2[c][j] = bf16rne(aw0 * bf2f(ed_f[c][j]) + aw1 * bf2f(t2[c][j]));
    }
    __builtin_amdgcn_sched_barrier(0);
    // dLA fused with ne = mLA*dLA -> t1
#pragma unroll
    for (int cb = 0; cb < 8; ++cb) {
        f32x4 v = gemm_cb(fragp, lane, 4, cb, t2);
        const int c = cb >> 1, jb = (cb & 1) * 4;
#pragma unroll
        for (int q = 0; q < 4; ++q)
            t1[c][jb + q] = bf16rne(bf2f(em_f[c][jb + q]) * v[q]);
    }
    __builtin_amdgcn_sched_barrier(0);
    // h = relu(ne@W1) ; pre = h . w2 ; out = sigmoid(pre)
    float pre = 0.f;
#pragma unroll
    for (int cb = 0; cb < 8; ++cb) {
        f32x4 v = gemm_cb(fragp, lane, 5, cb, t1);
        const int col = 16 * cb + 4 * g;
        float4 wv = *(const float4*)(w2 + col);
        pre += fmaxf(v[0], 0.f) * wv.x;
        pre += fmaxf(v[1], 0.f) * wv.y;
        pre += fmaxf(v[2], 0.f) * wv.z;
        pre += fmaxf(v[3], 0.f) * wv.w;
    }
    pre += __shfl_xor(pre, 16);
    pre += __shfl_xor(pre, 32);
    if (g == 0) out[row] = 1.f / (1.f + __expf(-pre));
}

extern "C" void kernel_launch(void* const* d_in, const int* in_sizes, int n_in,
                              void* d_out, int out_size, void* d_ws, size_t ws_size,
                              hipStream_t stream) {
    const float* em    = (const float*)d_in[0];
    const float* ed    = (const float*)d_in[1];
    const float* W_gcn = (const float*)d_in[2];
    const float* Wq_m  = (const float*)d_in[3];
    const float* Wk_m  = (const float*)d_in[4];
    const float* Wv_m  = (const float*)d_in[5];
    const float* Wq_d  = (const float*)d_in[6];
    const float* Wk_d  = (const float*)d_in[7];
    const float* Wv_d  = (const float*)d_in[8];
    const float* W1    = (const float*)d_in[9];
    const float* W2    = (const float*)d_in[10];
    float* out = (float*)d_out;

    float* M_m = (float*)d_ws;                         // 128*128 fp32
    float* M_d = M_m + 128 * 128;                      // 128*128 fp32
    unsigned short* frags = (unsigned short*)(M_d + 128 * 128);  // 6*16384 bf16

    const int B = in_sizes[0] / 128;                   // 262144

    hipLaunchKernelGGL(k_matmul_qkT, dim3(64), dim3(256), 0, stream, Wq_m, Wk_m, M_m);
    hipLaunchKernelGGL(k_matmul_qkT, dim3(64), dim3(256), 0, stream, Wq_d, Wk_d, M_d);
    hipLaunchKernelGGL(k_pack, dim3(384), dim3(256), 0, stream,
                       W_gcn, M_m, M_d, Wv_m, Wv_d, W1, frags);
    hipLaunchKernelGGL(k_main, dim3(B / 64), dim3(256), 0, stream,
                       em, ed, frags, W2, out);
}